// Round 6
// baseline (813.015 us; speedup 1.0000x reference)
//
#include <hip/hip_runtime.h>
#include <hip/hip_bf16.h>

// Mix2Layer: out[b,o] = sum_k relu(sum_i x[b,i]*w1[i,o,k] + b1[o,k]) * (sum_i x[b,i]*w2[i,o,k]) + b2[o]
// B=2048, DIN=2048, DOUT=2048, K=16.  N' = o*16+k (w row-major [DIN][32768]).
//
// Fast path (needs ws >= 264MB):
//   1) xcvt:   x fp32 -> bf16                  (8 MB)
//   2) wtrans: w[i][n'] fp32 -> wt[n'][i] bf16 (128 MB each)
//   3) mix2_gemmw: ring-of-4 PAIR-WINDOW schedule:
//      per pair {barA; STG(h+2),STG(h+3); vmcnt(8); barB; compute h,h+1}.
//      2-pair prefetch distance (wait ~free), 64-MFMA barrier-free windows,
//      compiler-counted lgkm interleave, global_load_lds w/ pre-swizzled src.
// Fallback: round-1 in-kernel-transpose kernel (verified passing).

typedef __bf16 bf16;
typedef bf16 bf16x8 __attribute__((ext_vector_type(8)));
typedef bf16 bf16x4 __attribute__((ext_vector_type(4)));
typedef float f32x4 __attribute__((ext_vector_type(4)));

typedef __attribute__((address_space(1))) const void gco_void;
typedef __attribute__((address_space(3))) void lds_void;

#define DIN_   2048
#define DOUT_  2048
#define NP_    32768   // DOUT*K

__device__ __forceinline__ bf16x8 cvt8(f32x4 a, f32x4 b) {
    bf16x8 v;
    v[0] = (bf16)a[0]; v[1] = (bf16)a[1]; v[2] = (bf16)a[2]; v[3] = (bf16)a[3];
    v[4] = (bf16)b[0]; v[5] = (bf16)b[1]; v[6] = (bf16)b[2]; v[7] = (bf16)b[3];
    return v;
}

// ---------------- prep 1: x fp32 -> bf16 ----------------
__global__ __launch_bounds__(256)
void xcvt(const float* __restrict__ x, bf16* __restrict__ xb) {
    const size_t i = ((size_t)blockIdx.x * 256 + threadIdx.x) * 8;
    f32x4 a = *(const f32x4*)(x + i);
    f32x4 b = *(const f32x4*)(x + i + 4);
    *(bf16x8*)(xb + i) = cvt8(a, b);
}

// ---------------- prep 2: w[i][n'] fp32 -> wt[n'][i] bf16 ----------------
__global__ __launch_bounds__(256)
void wtrans(const float* __restrict__ w1, const float* __restrict__ w2,
            bf16* __restrict__ w1t, bf16* __restrict__ w2t) {
    __shared__ float s[64][65];
    const int t  = threadIdx.x;
    const int lr = t >> 4;      // 0..15
    const int lq = t & 15;      // 0..15
    const int n0 = blockIdx.x * 64;
    const int i0 = blockIdx.y * 64;
    const float* src = blockIdx.z ? w2 : w1;
    bf16*        dst = blockIdx.z ? w2t : w1t;
#pragma unroll
    for (int r = 0; r < 4; ++r) {
        const int il = lr + 16 * r;
        f32x4 v = *(const f32x4*)(src + (size_t)(i0 + il) * NP_ + n0 + lq * 4);
        s[il][lq * 4 + 0] = v[0]; s[il][lq * 4 + 1] = v[1];
        s[il][lq * 4 + 2] = v[2]; s[il][lq * 4 + 3] = v[3];
    }
    __syncthreads();
#pragma unroll
    for (int r = 0; r < 4; ++r) {
        const int nl = lr + 16 * r;
        bf16x4 o;
        o[0] = (bf16)s[lq * 4 + 0][nl]; o[1] = (bf16)s[lq * 4 + 1][nl];
        o[2] = (bf16)s[lq * 4 + 2][nl]; o[3] = (bf16)s[lq * 4 + 3][nl];
        *(bf16x4*)(dst + (size_t)(n0 + nl) * DIN_ + i0 + lq * 4) = o;
    }
}

// ---------------- main: ring-of-4 pair-window dual-B GEMM ----------------
// Tile 256(m) x 128(n'); 64 K-halves of 32 k; ring of 4 LDS regions (32KB):
//   region r = h&3: [A 256x32k 16KB][B1 128x32k 8KB][B2 128x32k 8KB]
// rows 64B; 16B slots pre-swizzled: phys = slot ^ ((row>>1)&3).
// Pair t (h=2t): barA (reads h-2,h-1 done) -> STG(h+2),STG(h+3) -> vmcnt(8)
// (S(h),S(h+1) landed; issued a full pair ago) -> barB -> compute h,h+1
// (64 MFMA + 24 ds_reads, barrier-free, compiler-counted lgkm).
__global__ __launch_bounds__(512, 2)
void mix2_gemmw(const bf16* __restrict__ xb, const bf16* __restrict__ w1t,
                const bf16* __restrict__ w2t, const float* __restrict__ b1,
                const float* __restrict__ b2, float* __restrict__ out)
{
    __shared__ alignas(16) char lds[131072];

    const int tid  = threadIdx.x;
    const int lane = tid & 63;
    const int wid  = tid >> 6;     // 0..7
    const int wm   = wid >> 2;     // 0..1  (128-row slab)
    const int wn   = wid & 3;      // 0..3  (32-col slab)
    const int lk   = lane & 15;
    const int lg   = lane >> 4;

    const int nwg = gridDim.x;     // 2048
    const int bid = (blockIdx.x & 7) * (nwg >> 3) + (blockIdx.x >> 3);
    const int mt  = bid & 7;       // 8 m-tiles of 256
    const int nt  = bid >> 3;      // 256 n-panels of 128

    // staging mapping: chunk c -> row=c>>2, phys slot=c&3 holds global slot^((row>>1)&3)
    const int srow = tid >> 2;                      // 0..127
    const int sswz = ((tid & 3) ^ ((srow >> 1) & 3)) * 8;
    const bf16* gA  = xb  + (size_t)(mt * 256 + srow) * DIN_ + sswz;   // +128*DIN_ for rows 128..255
    const bf16* gB1 = w1t + (size_t)(nt * 128 + srow) * DIN_ + sswz;
    const bf16* gB2 = w2t + (size_t)(nt * 128 + srow) * DIN_ + sswz;

    // fragment read offsets (bytes within a region)
    const int kswz = (lg ^ ((lk >> 1) & 3)) * 16;
    int aoff[8], boff[2];
#pragma unroll
    for (int fm = 0; fm < 8; ++fm) aoff[fm] = (wm * 128 + fm * 16 + lk) * 64 + kswz;
#pragma unroll
    for (int fn = 0; fn < 2; ++fn) boff[fn] = (wn * 32 + fn * 16 + lk) * 64 + kswz;

    f32x4 acc1[8][2], acc2[8][2];
#pragma unroll
    for (int i = 0; i < 8; ++i)
#pragma unroll
        for (int j = 0; j < 2; ++j) {
            acc1[i][j] = (f32x4){0.f, 0.f, 0.f, 0.f};
            acc2[i][j] = (f32x4){0.f, 0.f, 0.f, 0.f};
        }

    const int ldw = wid * 1024;
    auto STG = [&](char* r, int koff) {   // 4 gload_lds into region r
        __builtin_amdgcn_global_load_lds((gco_void*)(gA  + koff),             (lds_void*)(r +         ldw), 16, 0, 0);
        __builtin_amdgcn_global_load_lds((gco_void*)(gA + 128 * DIN_ + koff), (lds_void*)(r +  8192 + ldw), 16, 0, 0);
        __builtin_amdgcn_global_load_lds((gco_void*)(gB1 + koff),             (lds_void*)(r + 16384 + ldw), 16, 0, 0);
        __builtin_amdgcn_global_load_lds((gco_void*)(gB2 + koff),             (lds_void*)(r + 24576 + ldw), 16, 0, 0);
    };

    auto COMPUTE = [&](const char* r) {   // 12 ds_read_b128 + 32 MFMA
        bf16x8 a[8], u[2], v[2];
#pragma unroll
        for (int fn = 0; fn < 2; ++fn) {
            u[fn] = *(const bf16x8*)(r + 16384 + boff[fn]);
            v[fn] = *(const bf16x8*)(r + 24576 + boff[fn]);
        }
#pragma unroll
        for (int fm = 0; fm < 8; ++fm) a[fm] = *(const bf16x8*)(r + aoff[fm]);
        __builtin_amdgcn_s_setprio(1);
#pragma unroll
        for (int fm = 0; fm < 8; ++fm)
#pragma unroll
            for (int fn = 0; fn < 2; ++fn) {
                acc1[fm][fn] = __builtin_amdgcn_mfma_f32_16x16x32_bf16(a[fm], u[fn], acc1[fm][fn], 0, 0, 0);
                acc2[fm][fn] = __builtin_amdgcn_mfma_f32_16x16x32_bf16(a[fm], v[fn], acc2[fm][fn], 0, 0, 0);
            }
        __builtin_amdgcn_s_setprio(0);
    };

    // prologue: stage halves 0,1
    STG(lds, 0);
    STG(lds + 32768, 32);

    // pairs t=0..30 (h=0..60): stage S(h+2),S(h+3) -> last staged = S(63)
#pragma unroll 1
    for (int t = 0; t < 31; ++t) {
        const int h = 2 * t;
        const char* rc0 = lds + ((h & 3) * 32768);
        const char* rc1 = lds + (((h + 1) & 3) * 32768);
        char* rs0 = lds + (((h + 2) & 3) * 32768);
        char* rs1 = lds + (((h + 3) & 3) * 32768);

        __builtin_amdgcn_s_barrier();                       // A: reads h-2,h-1 done
        __builtin_amdgcn_sched_barrier(0);
        STG(rs0, (h + 2) * 32);
        STG(rs1, (h + 3) * 32);
        asm volatile("s_waitcnt vmcnt(8)" ::: "memory");    // S(h),S(h+1) landed (this wave)
        __builtin_amdgcn_s_barrier();                       // B: landed for all waves
        __builtin_amdgcn_sched_barrier(0);
        COMPUTE(rc0);
        COMPUTE(rc1);
    }
    // tail pair h=62 (regions 2,3)
    __builtin_amdgcn_s_barrier();
    asm volatile("s_waitcnt vmcnt(0)" ::: "memory");
    __builtin_amdgcn_s_barrier();
    __builtin_amdgcn_sched_barrier(0);
    COMPUTE(lds + 2 * 32768);
    COMPUTE(lds + 3 * 32768);

    // ---- epilogue: k-reduce via shfl_xor, cols lane&15 = 16 k's of one o ----
    const int obase = nt * 8 + wn * 2;
#pragma unroll
    for (int fn = 0; fn < 2; ++fn) {
        const int o = obase + fn;
        const float bb1 = b1[(size_t)o * 16 + lk];
        const float bb2 = b2[o];
#pragma unroll
        for (int fm = 0; fm < 8; ++fm) {
#pragma unroll
            for (int j = 0; j < 4; ++j) {
                float g = fmaxf(acc1[fm][fn][j] + bb1, 0.f);
                float p = g * acc2[fm][fn][j];
                p += __shfl_xor(p, 1);
                p += __shfl_xor(p, 2);
                p += __shfl_xor(p, 4);
                p += __shfl_xor(p, 8);
                if (lk == 0) {
                    const int brow = mt * 256 + wm * 128 + fm * 16 + lg * 4 + j;
                    out[(size_t)brow * DOUT_ + o] = p + bb2;
                }
            }
        }
    }
}

// ---------------- fallback: round-1 kernel (verified passing) ----------------
__global__ __launch_bounds__(512)
void mix2_fused_direct(const float* __restrict__ x, const float* __restrict__ w1,
                       const float* __restrict__ b1, const float* __restrict__ w2,
                       const float* __restrict__ b2, float* __restrict__ out)
{
    __shared__ alignas(16) char lds[2 * 49152];

    const int tid  = threadIdx.x;
    const int lane = tid & 63;
    const int wid  = tid >> 6;
    const int wm   = wid >> 2;
    const int wn   = wid & 3;

    const int nwg = gridDim.x;
    const int bid = (blockIdx.x & 7) * (nwg >> 3) + (blockIdx.x >> 3);
    const int mt  = bid & 15;
    const int nt  = bid >> 4;

    const int lk  = lane & 15;
    const int lg  = lane >> 4;
    const int swz = (lane & 7) << 4;

    const int a_row  = tid >> 3;
    const int a_col8 = tid & 7;
    const int b_ib = ((tid >> 5) & 15) << 2;
    const int b_nb = (tid & 31) << 2;

    const float* pa  = x  + (size_t)(mt * 128 + a_row) * DIN_ + a_col8 * 8;
    const float* pb1 = w1 + (size_t)b_ib * NP_ + (size_t)nt * 128 + b_nb;
    const float* pb2 = w2 + (size_t)b_ib * NP_ + (size_t)nt * 128 + b_nb;

    const int aswz   = (a_col8 * 16) ^ ((a_row & 7) << 4);
    const int aoffw0 = a_row * 128 + aswz;
    const int aoffw1 = (a_row + 64) * 128 + aswz;

    int aoff[4], boff1[2], boff2[2];
#pragma unroll
    for (int fm = 0; fm < 4; ++fm) aoff[fm] = (wm * 64 + fm * 16 + lk) * 128;
#pragma unroll
    for (int fn = 0; fn < 2; ++fn) {
        const int n = wn * 32 + fn * 16 + lk;
        boff1[fn] = 16384 + n * 128;
        boff2[fn] = 32768 + n * 128;
    }
    const int kp0 = (lg * 16) ^ swz;
    const int kp1 = (64 + lg * 16) ^ swz;

    f32x4 acc1[4][2], acc2[4][2];
#pragma unroll
    for (int i = 0; i < 4; ++i)
#pragma unroll
        for (int j = 0; j < 2; ++j) {
            acc1[i][j] = (f32x4){0.f, 0.f, 0.f, 0.f};
            acc2[i][j] = (f32x4){0.f, 0.f, 0.f, 0.f};
        }

    f32x4 rA[4], rB1[4], rB2[4];

    auto LOAD = [&](int kt) {
        const float* a0 = pa + kt * 64;
        rA[0] = *(const f32x4*)(a0);
        rA[1] = *(const f32x4*)(a0 + 4);
        rA[2] = *(const f32x4*)(a0 + (size_t)64 * DIN_);
        rA[3] = *(const f32x4*)(a0 + (size_t)64 * DIN_ + 4);
        const float* q1 = pb1 + (size_t)kt * 64 * NP_;
        const float* q2 = pb2 + (size_t)kt * 64 * NP_;
#pragma unroll
        for (int j = 0; j < 4; ++j) {
            rB1[j] = *(const f32x4*)(q1 + (size_t)j * NP_);
            rB2[j] = *(const f32x4*)(q2 + (size_t)j * NP_);
        }
    };

    auto STORE = [&](char* s) {
        *(bf16x8*)(s + aoffw0) = cvt8(rA[0], rA[1]);
        *(bf16x8*)(s + aoffw1) = cvt8(rA[2], rA[3]);
        char* s1 = s + 16384;
        char* s2 = s + 32768;
#pragma unroll
        for (int c = 0; c < 4; ++c) {
            const int n   = b_nb + c;
            const int off = n * 128 + ((b_ib * 2) ^ ((n & 7) << 4));
            bf16x4 v1, v2;
            v1[0] = (bf16)rB1[0][c]; v1[1] = (bf16)rB1[1][c];
            v1[2] = (bf16)rB1[2][c]; v1[3] = (bf16)rB1[3][c];
            v2[0] = (bf16)rB2[0][c]; v2[1] = (bf16)rB2[1][c];
            v2[2] = (bf16)rB2[2][c]; v2[3] = (bf16)rB2[3][c];
            *(bf16x4*)(s1 + off) = v1;
            *(bf16x4*)(s2 + off) = v2;
        }
    };

    auto COMPUTE = [&](const char* s) {
#pragma unroll
        for (int kb = 0; kb < 2; ++kb) {
            const int kp = kb ? kp1 : kp0;
            bf16x8 a[4], u[2], v[2];
#pragma unroll
            for (int fm = 0; fm < 4; ++fm) a[fm] = *(const bf16x8*)(s + aoff[fm] + kp);
#pragma unroll
            for (int fn = 0; fn < 2; ++fn) u[fn] = *(const bf16x8*)(s + boff1[fn] + kp);
#pragma unroll
            for (int fn = 0; fn < 2; ++fn) v[fn] = *(const bf16x8*)(s + boff2[fn] + kp);
#pragma unroll
            for (int fm = 0; fm < 4; ++fm)
#pragma unroll
                for (int fn = 0; fn < 2; ++fn) {
                    acc1[fm][fn] = __builtin_amdgcn_mfma_f32_16x16x32_bf16(a[fm], u[fn], acc1[fm][fn], 0, 0, 0);
                    acc2[fm][fn] = __builtin_amdgcn_mfma_f32_16x16x32_bf16(a[fm], v[fn], acc2[fm][fn], 0, 0, 0);
                }
        }
    };

    char* buf0 = lds;
    char* buf1 = lds + 49152;

    LOAD(0);
    STORE(buf0);
    __syncthreads();

    for (int kt = 0; kt < 32; ++kt) {
        if (kt + 1 < 32) LOAD(kt + 1);
        COMPUTE((kt & 1) ? buf1 : buf0);
        if (kt + 1 < 32) {
            STORE((kt & 1) ? buf0 : buf1);
            __syncthreads();
        }
    }

    const int obase = nt * 8 + wn * 2;
#pragma unroll
    for (int fn = 0; fn < 2; ++fn) {
        const int o = obase + fn;
        const float bb1 = b1[(size_t)o * 16 + lk];
        const float bb2 = b2[o];
#pragma unroll
        for (int fm = 0; fm < 4; ++fm) {
#pragma unroll
            for (int j = 0; j < 4; ++j) {
                float g = fmaxf(acc1[fm][fn][j] + bb1, 0.f);
                float p = g * acc2[fm][fn][j];
                p += __shfl_xor(p, 1);
                p += __shfl_xor(p, 2);
                p += __shfl_xor(p, 4);
                p += __shfl_xor(p, 8);
                if (lk == 0) {
                    const int brow = mt * 128 + wm * 64 + fm * 16 + lg * 4 + j;
                    out[(size_t)brow * DOUT_ + o] = p + bb2;
                }
            }
        }
    }
}

extern "C" void kernel_launch(void* const* d_in, const int* in_sizes, int n_in,
                              void* d_out, int out_size, void* d_ws, size_t ws_size,
                              hipStream_t stream) {
    (void)in_sizes; (void)n_in; (void)out_size;
    const float* x  = (const float*)d_in[0];
    const float* w1 = (const float*)d_in[1];
    const float* b1 = (const float*)d_in[2];
    const float* w2 = (const float*)d_in[3];
    const float* b2 = (const float*)d_in[4];
    float* out = (float*)d_out;

    const size_t XB   = (size_t)DIN_ * DIN_ * 2;            // 8 MB   (x bf16)
    const size_t WT   = (size_t)NP_ * DIN_ * 2;             // 128 MB (each wt)
    const size_t NEED = XB + 2 * WT;                        // 264 MB

    if (ws_size >= NEED) {
        bf16* xb  = (bf16*)d_ws;
        bf16* w1t = (bf16*)((char*)d_ws + XB);
        bf16* w2t = (bf16*)((char*)d_ws + XB + WT);
        hipLaunchKernelGGL(xcvt,   dim3(2048),       dim3(256), 0, stream, x, xb);
        hipLaunchKernelGGL(wtrans, dim3(512, 32, 2), dim3(256), 0, stream, w1, w2, w1t, w2t);
        hipLaunchKernelGGL(mix2_gemmw, dim3(2048),   dim3(512), 0, stream, xb, w1t, w2t, b1, b2, out);
    } else {
        hipLaunchKernelGGL(mix2_fused_direct, dim3(4096), dim3(512), 0, stream, x, w1, b1, w2, b2, out);
    }
}

// Round 7
// 680.132 us; speedup vs baseline: 1.1954x; 1.1954x over previous
//
#include <hip/hip_runtime.h>
#include <hip/hip_bf16.h>

// Mix2Layer: out[b,o] = sum_k relu(sum_i x[b,i]*w1[i,o,k] + b1[o,k]) * (sum_i x[b,i]*w2[i,o,k]) + b2[o]
// B=2048, DIN=2048, DOUT=2048, K=16.  N' = o*16+k (w row-major [DIN][32768]).
//
// Fast path (needs ws >= 264MB):
//   1) xcvt:   x fp32 -> bf16                  (8 MB)
//   2) wtrans: w[i][n'] fp32 -> wt[n'][i] bf16 (128 MB each)
//   3) mix2_gemm8p: m201-faithful 8-phase schedule on ring-of-4 half-tiles:
//      per half (k32): 2 phases of {reads + 2 gload_lds; bar; lgkmcnt(0);
//      setprio; 16 MFMA; setprio; bar}, ONE counted vmcnt(8) per half at
//      phase-B end (3 half-tiles in flight), pre-swizzled gload_lds staging.
// Fallback: round-1 in-kernel-transpose kernel (verified passing).

typedef __bf16 bf16;
typedef bf16 bf16x8 __attribute__((ext_vector_type(8)));
typedef bf16 bf16x4 __attribute__((ext_vector_type(4)));
typedef float f32x4 __attribute__((ext_vector_type(4)));

typedef __attribute__((address_space(1))) const void gco_void;
typedef __attribute__((address_space(3))) void lds_void;

#define DIN_   2048
#define DOUT_  2048
#define NP_    32768   // DOUT*K

__device__ __forceinline__ bf16x8 cvt8(f32x4 a, f32x4 b) {
    bf16x8 v;
    v[0] = (bf16)a[0]; v[1] = (bf16)a[1]; v[2] = (bf16)a[2]; v[3] = (bf16)a[3];
    v[4] = (bf16)b[0]; v[5] = (bf16)b[1]; v[6] = (bf16)b[2]; v[7] = (bf16)b[3];
    return v;
}

// ---------------- prep 1: x fp32 -> bf16 ----------------
__global__ __launch_bounds__(256)
void xcvt(const float* __restrict__ x, bf16* __restrict__ xb) {
    const size_t i = ((size_t)blockIdx.x * 256 + threadIdx.x) * 8;
    f32x4 a = *(const f32x4*)(x + i);
    f32x4 b = *(const f32x4*)(x + i + 4);
    *(bf16x8*)(xb + i) = cvt8(a, b);
}

// ---------------- prep 2: w[i][n'] fp32 -> wt[n'][i] bf16 ----------------
__global__ __launch_bounds__(256)
void wtrans(const float* __restrict__ w1, const float* __restrict__ w2,
            bf16* __restrict__ w1t, bf16* __restrict__ w2t) {
    __shared__ float s[64][65];
    const int t  = threadIdx.x;
    const int lr = t >> 4;      // 0..15
    const int lq = t & 15;      // 0..15
    const int n0 = blockIdx.x * 64;
    const int i0 = blockIdx.y * 64;
    const float* src = blockIdx.z ? w2 : w1;
    bf16*        dst = blockIdx.z ? w2t : w1t;
#pragma unroll
    for (int r = 0; r < 4; ++r) {
        const int il = lr + 16 * r;
        f32x4 v = *(const f32x4*)(src + (size_t)(i0 + il) * NP_ + n0 + lq * 4);
        s[il][lq * 4 + 0] = v[0]; s[il][lq * 4 + 1] = v[1];
        s[il][lq * 4 + 2] = v[2]; s[il][lq * 4 + 3] = v[3];
    }
    __syncthreads();
#pragma unroll
    for (int r = 0; r < 4; ++r) {
        const int nl = lr + 16 * r;
        bf16x4 o;
        o[0] = (bf16)s[lq * 4 + 0][nl]; o[1] = (bf16)s[lq * 4 + 1][nl];
        o[2] = (bf16)s[lq * 4 + 2][nl]; o[3] = (bf16)s[lq * 4 + 3][nl];
        *(bf16x4*)(dst + (size_t)(n0 + nl) * DIN_ + i0 + lq * 4) = o;
    }
}

// ---------------- main: m201-style 8-phase dual-B GEMM ----------------
// Tile 256(m) x 128(n'); 64 K-halves of 32 k; ring of 4 LDS regions (32KB):
//   region r = h&3: [A 256x32k 16KB][B1 128x32k 8KB][B2 128x32k 8KB]
// rows 64B; 16B slots pre-swizzled: phys = slot ^ ((row>>1)&3).
// Half h: phase A {4 B-reads + 4 A-reads; STG_A(h+3); bar; lgkm0; 16 MFMA; bar}
//         phase B {4 A-reads; STG_B(h+3); bar; lgkm0; 16 MFMA; vmcnt(8); bar}
// vmcnt(8) at half-end covers S(h+1) for next half (S(h+2),S(h+3) in flight).
__global__ __launch_bounds__(512, 2)
void mix2_gemm8p(const bf16* __restrict__ xb, const bf16* __restrict__ w1t,
                 const bf16* __restrict__ w2t, const float* __restrict__ b1,
                 const float* __restrict__ b2, float* __restrict__ out)
{
    __shared__ alignas(16) char lds[131072];

    const int tid  = threadIdx.x;
    const int lane = tid & 63;
    const int wid  = tid >> 6;     // 0..7
    const int wm   = wid >> 2;     // 0..1  (128-row slab)
    const int wn   = wid & 3;      // 0..3  (32-col slab)
    const int lk   = lane & 15;
    const int lg   = lane >> 4;

    const int nwg = gridDim.x;     // 2048
    const int bid = (blockIdx.x & 7) * (nwg >> 3) + (blockIdx.x >> 3);
    const int mt  = bid & 7;       // 8 m-tiles of 256
    const int nt  = bid >> 3;      // 256 n-panels of 128

    // staging mapping: chunk c -> row=c>>2, phys slot=c&3 holds global slot^((row>>1)&3)
    const int srow = tid >> 2;                      // 0..127
    const int sswz = ((tid & 3) ^ ((srow >> 1) & 3)) * 8;
    const bf16* gA  = xb  + (size_t)(mt * 256 + srow) * DIN_ + sswz;   // +128*DIN_ for rows 128..255
    const bf16* gB1 = w1t + (size_t)(nt * 128 + srow) * DIN_ + sswz;
    const bf16* gB2 = w2t + (size_t)(nt * 128 + srow) * DIN_ + sswz;

    // fragment read offsets (bytes within a region)
    const int kswz = (lg ^ ((lk >> 1) & 3)) * 16;
    int aoff[8], boff[2];
#pragma unroll
    for (int fm = 0; fm < 8; ++fm) aoff[fm] = (wm * 128 + fm * 16 + lk) * 64 + kswz;
#pragma unroll
    for (int fn = 0; fn < 2; ++fn) boff[fn] = (wn * 32 + fn * 16 + lk) * 64 + kswz;

    f32x4 acc1[8][2], acc2[8][2];
#pragma unroll
    for (int i = 0; i < 8; ++i)
#pragma unroll
        for (int j = 0; j < 2; ++j) {
            acc1[i][j] = (f32x4){0.f, 0.f, 0.f, 0.f};
            acc2[i][j] = (f32x4){0.f, 0.f, 0.f, 0.f};
        }

    const int ldw = wid * 1024;
    auto STG_A = [&](int h) {      // A-halves of S(h): 2 gload_lds
        char* r = lds + (h & 3) * 32768;
        const int koff = h * 32;
        __builtin_amdgcn_global_load_lds((gco_void*)(gA  + koff),             (lds_void*)(r +        ldw), 16, 0, 0);
        __builtin_amdgcn_global_load_lds((gco_void*)(gA + 128 * DIN_ + koff), (lds_void*)(r + 8192 + ldw), 16, 0, 0);
    };
    auto STG_B = [&](int h) {      // B-halves of S(h): 2 gload_lds
        char* r = lds + (h & 3) * 32768;
        const int koff = h * 32;
        __builtin_amdgcn_global_load_lds((gco_void*)(gB1 + koff), (lds_void*)(r + 16384 + ldw), 16, 0, 0);
        __builtin_amdgcn_global_load_lds((gco_void*)(gB2 + koff), (lds_void*)(r + 24576 + ldw), 16, 0, 0);
    };

// one half-tile h: 2 phases, m201 template shape.
// W is the vmcnt immediate (token) applied at phase-B end.
#define HALF(h, DO_STG, W) do {                                              \
    const char* r_ = lds + (((h) & 3) * 32768);                              \
    bf16x8 u[2], v[2], a0[4], a1[4];                                         \
    /* ---- phase A ---- */                                                  \
    _Pragma("unroll") for (int fn_ = 0; fn_ < 2; ++fn_) {                    \
        u[fn_] = *(const bf16x8*)(r_ + 16384 + boff[fn_]);                   \
        v[fn_] = *(const bf16x8*)(r_ + 24576 + boff[fn_]);                   \
    }                                                                        \
    _Pragma("unroll") for (int j_ = 0; j_ < 4; ++j_)                         \
        a0[j_] = *(const bf16x8*)(r_ + aoff[j_]);                            \
    if (DO_STG) STG_A((h) + 3);                                              \
    __builtin_amdgcn_s_barrier();                                            \
    asm volatile("s_waitcnt lgkmcnt(0)" ::: "memory");                       \
    __builtin_amdgcn_sched_barrier(0);                                       \
    __builtin_amdgcn_s_setprio(1);                                           \
    _Pragma("unroll") for (int j_ = 0; j_ < 4; ++j_)                         \
        _Pragma("unroll") for (int fn_ = 0; fn_ < 2; ++fn_) {                \
            acc1[j_][fn_] = __builtin_amdgcn_mfma_f32_16x16x32_bf16(a0[j_], u[fn_], acc1[j_][fn_], 0, 0, 0); \
            acc2[j_][fn_] = __builtin_amdgcn_mfma_f32_16x16x32_bf16(a0[j_], v[fn_], acc2[j_][fn_], 0, 0, 0); \
        }                                                                    \
    __builtin_amdgcn_s_setprio(0);                                           \
    __builtin_amdgcn_s_barrier();                                            \
    /* ---- phase B ---- */                                                  \
    _Pragma("unroll") for (int j_ = 0; j_ < 4; ++j_)                         \
        a1[j_] = *(const bf16x8*)(r_ + aoff[4 + j_]);                        \
    if (DO_STG) STG_B((h) + 3);                                              \
    __builtin_amdgcn_s_barrier();                                            \
    asm volatile("s_waitcnt lgkmcnt(0)" ::: "memory");                       \
    __builtin_amdgcn_sched_barrier(0);                                       \
    __builtin_amdgcn_s_setprio(1);                                           \
    _Pragma("unroll") for (int j_ = 0; j_ < 4; ++j_)                         \
        _Pragma("unroll") for (int fn_ = 0; fn_ < 2; ++fn_) {                \
            acc1[4 + j_][fn_] = __builtin_amdgcn_mfma_f32_16x16x32_bf16(a1[j_], u[fn_], acc1[4 + j_][fn_], 0, 0, 0); \
            acc2[4 + j_][fn_] = __builtin_amdgcn_mfma_f32_16x16x32_bf16(a1[j_], v[fn_], acc2[4 + j_][fn_], 0, 0, 0); \
        }                                                                    \
    __builtin_amdgcn_s_setprio(0);                                           \
    asm volatile("s_waitcnt vmcnt(" #W ")" ::: "memory");                    \
    __builtin_amdgcn_s_barrier();                                            \
} while (0)

    // prologue: stage halves 0,1,2 (12 loads); wait S(0); publish
    STG_A(0); STG_B(0); STG_A(1); STG_B(1); STG_A(2); STG_B(2);
    asm volatile("s_waitcnt vmcnt(8)" ::: "memory");
    __builtin_amdgcn_s_barrier();
    __builtin_amdgcn_sched_barrier(0);

    // halves 0..59 (stage S(3)..S(62)); regions static under 4x unroll
#pragma unroll 1
    for (int t = 0; t < 15; ++t) {
        const int h0 = t * 4;
        HALF(h0 + 0, true, 8);
        HALF(h0 + 1, true, 8);
        HALF(h0 + 2, true, 8);
        HALF(h0 + 3, true, 8);
    }
    // tail: 60 stages S(63); then drain
    HALF(60, true, 8);
    HALF(61, false, 4);
    HALF(62, false, 0);
    HALF(63, false, 0);

#undef HALF

    // ---- epilogue: k-reduce via shfl_xor, cols lane&15 = 16 k's of one o ----
    const int obase = nt * 8 + wn * 2;
#pragma unroll
    for (int fn = 0; fn < 2; ++fn) {
        const int o = obase + fn;
        const float bb1 = b1[(size_t)o * 16 + lk];
        const float bb2 = b2[o];
#pragma unroll
        for (int fm = 0; fm < 8; ++fm) {
#pragma unroll
            for (int j = 0; j < 4; ++j) {
                float g = fmaxf(acc1[fm][fn][j] + bb1, 0.f);
                float p = g * acc2[fm][fn][j];
                p += __shfl_xor(p, 1);
                p += __shfl_xor(p, 2);
                p += __shfl_xor(p, 4);
                p += __shfl_xor(p, 8);
                if (lk == 0) {
                    const int brow = mt * 256 + wm * 128 + fm * 16 + lg * 4 + j;
                    out[(size_t)brow * DOUT_ + o] = p + bb2;
                }
            }
        }
    }
}

// ---------------- fallback: round-1 kernel (verified passing) ----------------
__global__ __launch_bounds__(512)
void mix2_fused_direct(const float* __restrict__ x, const float* __restrict__ w1,
                       const float* __restrict__ b1, const float* __restrict__ w2,
                       const float* __restrict__ b2, float* __restrict__ out)
{
    __shared__ alignas(16) char lds[2 * 49152];

    const int tid  = threadIdx.x;
    const int lane = tid & 63;
    const int wid  = tid >> 6;
    const int wm   = wid >> 2;
    const int wn   = wid & 3;

    const int nwg = gridDim.x;
    const int bid = (blockIdx.x & 7) * (nwg >> 3) + (blockIdx.x >> 3);
    const int mt  = bid & 15;
    const int nt  = bid >> 4;

    const int lk  = lane & 15;
    const int lg  = lane >> 4;
    const int swz = (lane & 7) << 4;

    const int a_row  = tid >> 3;
    const int a_col8 = tid & 7;
    const int b_ib = ((tid >> 5) & 15) << 2;
    const int b_nb = (tid & 31) << 2;

    const float* pa  = x  + (size_t)(mt * 128 + a_row) * DIN_ + a_col8 * 8;
    const float* pb1 = w1 + (size_t)b_ib * NP_ + (size_t)nt * 128 + b_nb;
    const float* pb2 = w2 + (size_t)b_ib * NP_ + (size_t)nt * 128 + b_nb;

    const int aswz   = (a_col8 * 16) ^ ((a_row & 7) << 4);
    const int aoffw0 = a_row * 128 + aswz;
    const int aoffw1 = (a_row + 64) * 128 + aswz;

    int aoff[4], boff1[2], boff2[2];
#pragma unroll
    for (int fm = 0; fm < 4; ++fm) aoff[fm] = (wm * 64 + fm * 16 + lk) * 128;
#pragma unroll
    for (int fn = 0; fn < 2; ++fn) {
        const int n = wn * 32 + fn * 16 + lk;
        boff1[fn] = 16384 + n * 128;
        boff2[fn] = 32768 + n * 128;
    }
    const int kp0 = (lg * 16) ^ swz;
    const int kp1 = (64 + lg * 16) ^ swz;

    f32x4 acc1[4][2], acc2[4][2];
#pragma unroll
    for (int i = 0; i < 4; ++i)
#pragma unroll
        for (int j = 0; j < 2; ++j) {
            acc1[i][j] = (f32x4){0.f, 0.f, 0.f, 0.f};
            acc2[i][j] = (f32x4){0.f, 0.f, 0.f, 0.f};
        }

    f32x4 rA[4], rB1[4], rB2[4];

    auto LOAD = [&](int kt) {
        const float* a0 = pa + kt * 64;
        rA[0] = *(const f32x4*)(a0);
        rA[1] = *(const f32x4*)(a0 + 4);
        rA[2] = *(const f32x4*)(a0 + (size_t)64 * DIN_);
        rA[3] = *(const f32x4*)(a0 + (size_t)64 * DIN_ + 4);
        const float* q1 = pb1 + (size_t)kt * 64 * NP_;
        const float* q2 = pb2 + (size_t)kt * 64 * NP_;
#pragma unroll
        for (int j = 0; j < 4; ++j) {
            rB1[j] = *(const f32x4*)(q1 + (size_t)j * NP_);
            rB2[j] = *(const f32x4*)(q2 + (size_t)j * NP_);
        }
    };

    auto STORE = [&](char* s) {
        *(bf16x8*)(s + aoffw0) = cvt8(rA[0], rA[1]);
        *(bf16x8*)(s + aoffw1) = cvt8(rA[2], rA[3]);
        char* s1 = s + 16384;
        char* s2 = s + 32768;
#pragma unroll
        for (int c = 0; c < 4; ++c) {
            const int n   = b_nb + c;
            const int off = n * 128 + ((b_ib * 2) ^ ((n & 7) << 4));
            bf16x4 v1, v2;
            v1[0] = (bf16)rB1[0][c]; v1[1] = (bf16)rB1[1][c];
            v1[2] = (bf16)rB1[2][c]; v1[3] = (bf16)rB1[3][c];
            v2[0] = (bf16)rB2[0][c]; v2[1] = (bf16)rB2[1][c];
            v2[2] = (bf16)rB2[2][c]; v2[3] = (bf16)rB2[3][c];
            *(bf16x4*)(s1 + off) = v1;
            *(bf16x4*)(s2 + off) = v2;
        }
    };

    auto COMPUTE = [&](const char* s) {
#pragma unroll
        for (int kb = 0; kb < 2; ++kb) {
            const int kp = kb ? kp1 : kp0;
            bf16x8 a[4], u[2], v[2];
#pragma unroll
            for (int fm = 0; fm < 4; ++fm) a[fm] = *(const bf16x8*)(s + aoff[fm] + kp);
#pragma unroll
            for (int fn = 0; fn < 2; ++fn) u[fn] = *(const bf16x8*)(s + boff1[fn] + kp);
#pragma unroll
            for (int fn = 0; fn < 2; ++fn) v[fn] = *(const bf16x8*)(s + boff2[fn] + kp);
#pragma unroll
            for (int fm = 0; fm < 4; ++fm)
#pragma unroll
                for (int fn = 0; fn < 2; ++fn) {
                    acc1[fm][fn] = __builtin_amdgcn_mfma_f32_16x16x32_bf16(a[fm], u[fn], acc1[fm][fn], 0, 0, 0);
                    acc2[fm][fn] = __builtin_amdgcn_mfma_f32_16x16x32_bf16(a[fm], v[fn], acc2[fm][fn], 0, 0, 0);
                }
        }
    };

    char* buf0 = lds;
    char* buf1 = lds + 49152;

    LOAD(0);
    STORE(buf0);
    __syncthreads();

    for (int kt = 0; kt < 32; ++kt) {
        if (kt + 1 < 32) LOAD(kt + 1);
        COMPUTE((kt & 1) ? buf1 : buf0);
        if (kt + 1 < 32) {
            STORE((kt & 1) ? buf0 : buf1);
            __syncthreads();
        }
    }

    const int obase = nt * 8 + wn * 2;
#pragma unroll
    for (int fn = 0; fn < 2; ++fn) {
        const int o = obase + fn;
        const float bb1 = b1[(size_t)o * 16 + lk];
        const float bb2 = b2[o];
#pragma unroll
        for (int fm = 0; fm < 4; ++fm) {
#pragma unroll
            for (int j = 0; j < 4; ++j) {
                float g = fmaxf(acc1[fm][fn][j] + bb1, 0.f);
                float p = g * acc2[fm][fn][j];
                p += __shfl_xor(p, 1);
                p += __shfl_xor(p, 2);
                p += __shfl_xor(p, 4);
                p += __shfl_xor(p, 8);
                if (lk == 0) {
                    const int brow = mt * 128 + wm * 64 + fm * 16 + lg * 4 + j;
                    out[(size_t)brow * DOUT_ + o] = p + bb2;
                }
            }
        }
    }
}

extern "C" void kernel_launch(void* const* d_in, const int* in_sizes, int n_in,
                              void* d_out, int out_size, void* d_ws, size_t ws_size,
                              hipStream_t stream) {
    (void)in_sizes; (void)n_in; (void)out_size;
    const float* x  = (const float*)d_in[0];
    const float* w1 = (const float*)d_in[1];
    const float* b1 = (const float*)d_in[2];
    const float* w2 = (const float*)d_in[3];
    const float* b2 = (const float*)d_in[4];
    float* out = (float*)d_out;

    const size_t XB   = (size_t)DIN_ * DIN_ * 2;            // 8 MB   (x bf16)
    const size_t WT   = (size_t)NP_ * DIN_ * 2;             // 128 MB (each wt)
    const size_t NEED = XB + 2 * WT;                        // 264 MB

    if (ws_size >= NEED) {
        bf16* xb  = (bf16*)d_ws;
        bf16* w1t = (bf16*)((char*)d_ws + XB);
        bf16* w2t = (bf16*)((char*)d_ws + XB + WT);
        hipLaunchKernelGGL(xcvt,   dim3(2048),       dim3(256), 0, stream, x, xb);
        hipLaunchKernelGGL(wtrans, dim3(512, 32, 2), dim3(256), 0, stream, w1, w2, w1t, w2t);
        hipLaunchKernelGGL(mix2_gemm8p, dim3(2048),  dim3(512), 0, stream, xb, w1t, w2t, b1, b2, out);
    } else {
        hipLaunchKernelGGL(mix2_fused_direct, dim3(4096), dim3(512), 0, stream, x, w1, b1, w2, b2, out);
    }
}